// Round 5
// baseline (122.137 us; speedup 1.0000x reference)
//
#include <hip/hip_runtime.h>
#include <hip/hip_bf16.h>
#include <math.h>

// Problem constants (NonLocalBlock): B=4, C=64, H=W=64 -> N=4096, CI=32
// Inputs/outputs are float32 (per reference); bf16 used internally for MFMA.
// Softmax trick: logits s[q][k] = x_q·x_k, shifted by K[q] = |x_q|^2 (diag).
// Cauchy-Schwarz bounds shifted logits <= ~35 and the shifted diag = 0, so
// exp never overflows and the denominator >= ~1: softmax becomes a PURE
// exp + linear accumulation; key-split partials combine by plain addition.
#define B_  4
#define C_  64
#define N_  4096
#define CI_ 32

typedef __attribute__((ext_vector_type(8))) unsigned short u16x8;
typedef __attribute__((ext_vector_type(8))) __bf16        bf16x8;
typedef __attribute__((ext_vector_type(4))) float         f32x4;

__device__ __forceinline__ unsigned short f2bf(float f) {
    union { float f; unsigned int i; } v; v.f = f;
    unsigned int r = v.i + 0x7FFFu + ((v.i >> 16) & 1u);
    return (unsigned short)(r >> 16);
}

// ---------------------------------------------------------------------------
// Kernel 1 (fused prep): per 64-n tile of one batch:
//   xT[b][n][c] (bf16) <- transpose of x;  gx[b][o][n] (bf16) <- Wg x + bg;
//   diag[b][n] (f32) <- |x_n|^2  (softmax shift)
// Grid 256 = b(4) x ntile(64). Block 256.
// ---------------------------------------------------------------------------
__global__ __launch_bounds__(256) void k_prep(
    const float* __restrict__ x, const float* __restrict__ Wg,
    const float* __restrict__ bg, unsigned short* __restrict__ xT,
    unsigned short* __restrict__ gx, float* __restrict__ diag)
{
    __shared__ __align__(16) float tile[64][68];   // stride 68: rows 16B-aligned
    __shared__ float part[4][64][33];              // o 0..31 = gx, col 32 = diag
    const int t  = threadIdx.x;
    const int b  = blockIdx.x >> 6;
    const int n0 = (blockIdx.x & 63) * 64;

    #pragma unroll
    for (int pass = 0; pass < 4; ++pass) {
        int c   = (t >> 4) + pass * 16;
        int nl4 = (t & 15) * 4;
        float4 v = *(const float4*)(x + (size_t)(b * C_ + c) * N_ + n0 + nl4);
        *(float4*)&tile[c][nl4] = v;
    }
    __syncthreads();

    // (a) write xT (bf16 transpose)
    {
        const int n  = t >> 2;
        const int cc = (t & 3) * 16;
        u16x8 a, b2;
        #pragma unroll
        for (int j = 0; j < 8; ++j) a[j]  = f2bf(tile[cc + j][n]);
        #pragma unroll
        for (int j = 0; j < 8; ++j) b2[j] = f2bf(tile[cc + 8 + j][n]);
        unsigned short* dst = xT + (size_t)(b * N_ + n0 + n) * C_ + cc;
        *(u16x8*)dst       = a;
        *(u16x8*)(dst + 8) = b2;
    }
    // (b) gx partial + diag partial
    {
        const int nl = t & 63, cq = t >> 6;
        float acc[CI_];
        #pragma unroll
        for (int o = 0; o < CI_; ++o) acc[o] = 0.f;
        float dd = 0.f;
        #pragma unroll 4
        for (int cl = 0; cl < 16; ++cl) {
            int c = cq * 16 + cl;
            float xv = tile[c][nl];
            dd += xv * xv;
            #pragma unroll
            for (int o = 0; o < CI_; ++o) acc[o] += Wg[o * C_ + c] * xv;
        }
        #pragma unroll
        for (int o = 0; o < CI_; ++o) part[cq][nl][o] = acc[o];
        part[cq][nl][32] = dd;
    }
    __syncthreads();
    // (c) reduce + write gx
    {
        const int o = t >> 3, nr = (t & 7) * 8;
        u16x8 w;
        #pragma unroll
        for (int j = 0; j < 8; ++j) {
            int n = nr + j;
            float s = part[0][n][o] + part[1][n][o] + part[2][n][o] + part[3][n][o]
                    + bg[o];
            w[j] = f2bf(s);
        }
        *(u16x8*)(gx + (size_t)(b * CI_ + o) * N_ + n0 + nr) = w;
    }
    // (d) write diag
    if (t < 64)
        diag[(size_t)b * N_ + n0 + t] =
            part[0][t][32] + part[1][t][32] + part[2][t][32] + part[3][t][32];
}

// ---------------------------------------------------------------------------
// Kernel 2: flash partial, shift-softmax, NO in-loop LDS staging / barriers.
// Grid 1024 = b(4) x qtile(64) x kq(4). Block 256 = 4 waves.
// Each wave: ALL 64 queries of the q-tile x a private 256-key subset
// (8 tiles of 32 keys). A/B MFMA fragments are loaded DIRECTLY from global
// (xT rows / gx rows are 16B-contiguous per lane; data is L2-resident).
// LDS is used only for the within-wave P C-layout->A-layout round trip
// (lgkmcnt-ordered, no barrier) and the final 4-wave additive merge.
// MFMA 16x16x32 bf16 layouts (verified):
//   A: [m=lane&15][k=quad*8+j]  B: [k=quad*8+j][n=lane&15]  D: row=quad*4+r, col=lane&15
// ---------------------------------------------------------------------------
__device__ __forceinline__ f32x4 mfma16(bf16x8 a, bf16x8 b, f32x4 c) {
    return __builtin_amdgcn_mfma_f32_16x16x32_bf16(a, b, c, 0, 0, 0);
}

__global__ __launch_bounds__(256, 3) void k_flash(
    const unsigned short* __restrict__ xT, const unsigned short* __restrict__ gx,
    const float* __restrict__ diag,
    float* __restrict__ ypart, float* __restrict__ lpart)
{
    __shared__ __align__(16) char smem[34816];
    unsigned short* Pl = (unsigned short*)smem;   // loop: [4 wave][64 q][40 key]
    float*          ym = (float*)smem;            // epilogue: [4 wave][64 q][34]

    const int tid  = threadIdx.x;
    const int wave = tid >> 6, lane = tid & 63;
    const int quad = lane >> 4, li = lane & 15;
    const int bi  = blockIdx.x;
    const int kq  = bi & 3;
    const int qtb = (bi >> 2) & 63;
    const int b   = bi >> 8;
    const int q0  = qtb * 64;

    const unsigned short* xTb = xT + (size_t)b * N_ * C_;
    const unsigned short* gxb = gx + (size_t)(b * CI_) * N_;

    // per-lane softmax shift: query = column li of S^T, per 16-q group qt
    float Kq[4];
    #pragma unroll
    for (int qt = 0; qt < 4; ++qt)
        Kq[qt] = diag[(size_t)b * N_ + q0 + qt * 16 + li];

    // Q fragments (B-operand), resident in registers: 4 x 16 queries
    bf16x8 Qf[4][2];
    #pragma unroll
    for (int qt = 0; qt < 4; ++qt)
        #pragma unroll
        for (int kc = 0; kc < 2; ++kc)
            Qf[qt][kc] = *(const bf16x8*)(xTb + (size_t)(q0 + qt * 16 + li) * C_
                                          + kc * 32 + quad * 8);

    f32x4 Yf[4][2];
    #pragma unroll
    for (int qt = 0; qt < 4; ++qt)
        #pragma unroll
        for (int ot = 0; ot < 2; ++ot)
            Yf[qt][ot] = (f32x4){0.f, 0.f, 0.f, 0.f};
    float lacc[4] = {0.f, 0.f, 0.f, 0.f};

    const int keybase = kq * 1024 + wave * 256;   // wave-private 256-key subset

    for (int tl = 0; tl < 8; ++tl) {
        const int k0 = keybase + tl * 32;

        // ---- direct global fragment loads (16B/lane, L2-hot) ----
        bf16x8 A[2][2];
        #pragma unroll
        for (int kt = 0; kt < 2; ++kt)
            #pragma unroll
            for (int kc = 0; kc < 2; ++kc)
                A[kt][kc] = *(const bf16x8*)(xTb + (size_t)(k0 + kt * 16 + li) * C_
                                             + kc * 32 + quad * 8);
        bf16x8 Bv[2];
        #pragma unroll
        for (int ot = 0; ot < 2; ++ot)
            Bv[ot] = *(const bf16x8*)(gxb + (size_t)(ot * 16 + li) * N_
                                      + k0 + quad * 8);

        // ---- S^T = K (32key x 64c) * Q (64c x 64q) ----
        f32x4 S[2][4];
        #pragma unroll
        for (int kt = 0; kt < 2; ++kt)
            #pragma unroll
            for (int qt = 0; qt < 4; ++qt) {
                f32x4 z = (f32x4){0.f, 0.f, 0.f, 0.f};
                z = mfma16(A[kt][0], Qf[qt][0], z);
                S[kt][qt] = mfma16(A[kt][1], Qf[qt][1], z);
            }

        // ---- p = exp(s - K[q]); accumulate l; P -> LDS (A-layout, in-wave) ----
        #pragma unroll
        for (int qt = 0; qt < 4; ++qt) {
            float p[2][4];
            #pragma unroll
            for (int kt = 0; kt < 2; ++kt)
                #pragma unroll
                for (int r = 0; r < 4; ++r) {
                    p[kt][r] = __expf(S[kt][qt][r] - Kq[qt]);
                    lacc[qt] += p[kt][r];
                }
            #pragma unroll
            for (int kt = 0; kt < 2; ++kt) {
                uint2 wv;
                wv.x = (unsigned)f2bf(p[kt][0]) | ((unsigned)f2bf(p[kt][1]) << 16);
                wv.y = (unsigned)f2bf(p[kt][2]) | ((unsigned)f2bf(p[kt][3]) << 16);
                *(uint2*)(Pl + (wave * 64 + qt * 16 + li) * 40 + kt * 16 + quad * 4) = wv;
            }
        }

        // ---- Y += P (64q x 32key) * V (32key x 32o) ----
        #pragma unroll
        for (int qt = 0; qt < 4; ++qt) {
            bf16x8 Ap = *(const bf16x8*)(Pl + (wave * 64 + qt * 16 + li) * 40 + quad * 8);
            #pragma unroll
            for (int ot = 0; ot < 2; ++ot)
                Yf[qt][ot] = mfma16(Ap, Bv[ot], Yf[qt][ot]);
        }
    }

    // finalize l: sum across quads (keys) -> every lane holds total for its query
    #pragma unroll
    for (int qt = 0; qt < 4; ++qt) {
        lacc[qt] += __shfl_xor(lacc[qt], 16, 64);
        lacc[qt] += __shfl_xor(lacc[qt], 32, 64);
    }

    __syncthreads();   // Pl dead; switch LDS to merge layout
    #pragma unroll
    for (int qt = 0; qt < 4; ++qt) {
        #pragma unroll
        for (int ot = 0; ot < 2; ++ot)
            #pragma unroll
            for (int r = 0; r < 4; ++r)
                ym[(wave * 64 + qt * 16 + quad * 4 + r) * 34 + ot * 16 + li] = Yf[qt][ot][r];
        if (quad == 0)
            ym[(wave * 64 + qt * 16 + li) * 34 + 32] = lacc[qt];
    }
    __syncthreads();
    {
        const int q = tid >> 2, og = tid & 3;
        const size_t pbase = (size_t)(b * 64 + qtb) * 4 + kq;
        float* yp = ypart + pbase * 2048 + q * 32;
        #pragma unroll
        for (int j = 0; j < 8; ++j) {
            int o = og * 8 + j;
            yp[o] = ym[(0 * 64 + q) * 34 + o] + ym[(1 * 64 + q) * 34 + o]
                  + ym[(2 * 64 + q) * 34 + o] + ym[(3 * 64 + q) * 34 + o];
        }
        if (og == 0)
            lpart[pbase * 64 + q] = ym[(0 * 64 + q) * 34 + 32] + ym[(1 * 64 + q) * 34 + 32]
                                  + ym[(2 * 64 + q) * 34 + 32] + ym[(3 * 64 + q) * 34 + 32];
    }
}

// ---------------------------------------------------------------------------
// Kernel 3: merge 4 key-quarter partials (plain add) + Wz epilogue + residual.
// Grid: 256 blocks = b x qtile. Block 256 threads.
// ---------------------------------------------------------------------------
__global__ __launch_bounds__(256) void k_merge(
    const float* __restrict__ ypart, const float* __restrict__ lpart,
    const float* __restrict__ x, const float* __restrict__ Wz,
    const float* __restrict__ bz, float* __restrict__ out)
{
    __shared__ float yfin[64][33];
    const int t   = threadIdx.x;
    const int b   = blockIdx.x >> 6;
    const int qtb = blockIdx.x & 63;
    const int q0  = qtb * 64;

    {
        const int q = t >> 2, og = t & 3;
        const size_t pb = (size_t)(b * 64 + qtb) * 4;
        float l = lpart[(pb + 0) * 64 + q] + lpart[(pb + 1) * 64 + q]
                + lpart[(pb + 2) * 64 + q] + lpart[(pb + 3) * 64 + q];
        float inv = 1.f / l;
        #pragma unroll
        for (int j = 0; j < 8; ++j) {
            int o = og * 8 + j;
            float acc = 0.f;
            #pragma unroll
            for (int kq = 0; kq < 4; ++kq)
                acc += ypart[(pb + kq) * 2048 + q * 32 + o];
            yfin[q][o] = acc * inv;
        }
    }
    __syncthreads();
    {
        const int q = t & 63, c0 = t >> 6;
        #pragma unroll
        for (int i = 0; i < 16; ++i) {
            int cout = c0 + i * 4;
            float acc = bz[cout];
            #pragma unroll
            for (int o = 0; o < CI_; ++o)
                acc += Wz[cout * CI_ + o] * yfin[q][o];
            size_t oidx = (size_t)(b * C_ + cout) * N_ + q0 + q;
            out[oidx] = acc + x[oidx];
        }
    }
}

// ---------------------------------------------------------------------------
extern "C" void kernel_launch(void* const* d_in, const int* in_sizes, int n_in,
                              void* d_out, int out_size, void* d_ws, size_t ws_size,
                              hipStream_t stream) {
    (void)in_sizes; (void)n_in; (void)out_size; (void)ws_size;
    const float* x  = (const float*)d_in[0];
    const float* Wg = (const float*)d_in[1];
    const float* bg = (const float*)d_in[2];
    const float* Wz = (const float*)d_in[3];
    const float* bz = (const float*)d_in[4];
    float* out = (float*)d_out;

    // ws layout: xT 2MB | gx 1MB | diag 64KB | ypart 8MB | lpart 256KB (~11.3MB)
    unsigned short* xT = (unsigned short*)d_ws;
    unsigned short* gx = (unsigned short*)((char*)d_ws + 2097152);
    float* diag  = (float*)((char*)d_ws + 3145728);
    float* ypart = (float*)((char*)d_ws + 3211264);
    float* lpart = (float*)((char*)d_ws + 11599872);

    hipLaunchKernelGGL(k_prep,  dim3(B_ * (N_ / 64)), dim3(256), 0, stream, x, Wg, bg, xT, gx, diag);
    hipLaunchKernelGGL(k_flash, dim3(B_ * 64 * 4),    dim3(256), 0, stream, xT, gx, diag, ypart, lpart);
    hipLaunchKernelGGL(k_merge, dim3(B_ * 64),        dim3(256), 0, stream, ypart, lpart, x, Wz, bz, out);
}